// Round 6
// baseline (91.838 us; speedup 1.0000x reference)
//
#include <hip/hip_runtime.h>

#define NW 10

// DPP: quad_perm xor1=0xB1, xor2=0x4E; row_ror:8 (xor8 within 16) = 0x128
template<int CTRL>
__device__ __forceinline__ float fdpp(float v) {
    return __int_as_float(__builtin_amdgcn_mov_dpp(__float_as_int(v), CTRL, 0xF, 0xF, true));
}
// ds_swizzle BitMode: xor4=0x101F, xor16=0x401F (reduction only)
template<int PAT>
__device__ __forceinline__ float fswz(float v) {
    return __int_as_float(__builtin_amdgcn_ds_swizzle(__float_as_int(v), PAT));
}

// ---- Layouts ----
// C : r0=s0 r1=s1 | l0=s2 l1=s3 l2=s4 l3=s5 l4=s6 l5=s7 | W0=s8 W1=s9
// L1: r0=s8 r1=s9 | l0=s4 l1=s6 l2=s2 l3=s7 l4=s3 l5=s5 | W0=s0 W1=s1
// element index e = lane | r<<6 | W<<8 in the layout's own coords.
__device__ __forceinline__ int sC(int W, int lane, int r) { return (W << 8) | (lane << 2) | r; }
__device__ __forceinline__ int sL1(int W, int lane, int r) {
    return ((r & 1) << 8) | (((r >> 1) & 1) << 9)
         | ((lane & 1) << 4) | (((lane >> 1) & 1) << 6) | (((lane >> 2) & 1) << 2)
         | (((lane >> 3) & 1) << 7) | (((lane >> 4) & 1) << 3) | (((lane >> 5) & 1) << 5)
         | ((W & 1) << 0) | (((W >> 1) & 1) << 1);
}
__device__ __forceinline__ int eC(int s) { return ((s >> 2) & 63) | ((s & 3) << 6) | ((s >> 8) << 8); }
__device__ __forceinline__ int eL1(int s) {
    const int lane = ((s >> 4) & 1) | (((s >> 6) & 1) << 1) | (((s >> 2) & 1) << 2)
                   | (((s >> 7) & 1) << 3) | (((s >> 3) & 1) << 4) | (((s >> 5) & 1) << 5);
    const int r = ((s >> 8) & 1) | (((s >> 9) & 1) << 1);
    const int W = (s & 1) | (((s >> 1) & 1) << 1);
    return lane | (r << 6) | (W << 8);
}

// ---------------- precompute: 14 diag tables (layout-aware) + 80 RY pairs ----------------
// d<3: rz0(k=d+1) [C] ; d<7: rz2(k=d-3) [L1] ; d<11: rz3(k=d-7) [C] ; d<14: rz5(k=d-11) [L1]
__global__ void precompute_kernel(const float* __restrict__ params, float2* __restrict__ tab) {
    const int d = blockIdx.x;
    const int j = threadIdx.x;
    if (d < 14) {
        int k, row; bool L1;
        if (d < 3)       { k = d + 1;  row = 0; L1 = false; }
        else if (d < 7)  { k = d - 3;  row = 2; L1 = true;  }
        else if (d < 11) { k = d - 7;  row = 3; L1 = false; }
        else             { k = d - 11; row = 5; L1 = true;  }
        const float* th = params + (k * 6 + row) * NW;
        const int W = j >> 8, lane = j & 63, r = (j >> 6) & 3;
        const int s = L1 ? sL1(W, lane, r) : sC(W, lane, r);
        float ang = 0.f;
#pragma unroll
        for (int w = 0; w < NW; ++w)
            ang += th[w] * (((s >> (9 - w)) & 1) ? 0.5f : -0.5f);
        float sn, cs;
        __sincosf(ang, &sn, &cs);
        tab[d * 1024 + j] = make_float2(cs, sn);
    } else if (j < 80) {
        const int ry = j / NW, w = j % NW;
        const int k = ry >> 1, i = ry & 1;
        const float* th = params + (k * 6 + (i ? 4 : 1)) * NW;
        float sn, cs;
        __sincosf(0.5f * th[w], &sn, &cs);
        tab[14 * 1024 + j] = make_float2(cs, sn);
    }
}

// ---------------- main kernel ----------------
__global__ __launch_bounds__(256, 8) void qsim_kernel(const float* __restrict__ x,
                                                      const float2* __restrict__ tab,
                                                      float* __restrict__ out) {
    __shared__ float2 buf[2][1024];
    __shared__ float sred[4][NW];

    const int t     = threadIdx.x;
    const int W     = t >> 6;
    const int lane  = t & 63;
    const int b     = blockIdx.x;
    const int ebase = lane | (W << 8);
    const float2* ry_tab = tab + 14 * 1024;

    float re[4], im[4];
#pragma unroll
    for (int r = 0; r < 4; ++r) { re[r] = 0.f; im[r] = 0.f; }
    if (t == 0) re[0] = 1.f;

    // retile-1 gather (C-data read while assuming L1 role) and fused perm gather
    // perm: new_C[s] = old_L1[q], q = s^(s>>1)^((s&1)*0x300)
    int riA[4], geidx[4];
#pragma unroll
    for (int r = 0; r < 4; ++r) {
        riA[r] = eC(sL1(W, lane, r));
        const int s = sC(W, lane, r);
        const int q = s ^ (s >> 1) ^ ((s & 1) * 0x300);
        geidx[r] = eL1(q);
    }

    // x-phase e^{iA_x(s)} (C layout), reused for the 3 encoding diagonals
    const float* xb = x + b * NW;
    float xr[4], xi[4];
    {
        float xv[NW];
#pragma unroll
        for (int w = 0; w < NW; ++w) xv[w] = xb[w];
        float A = 0.f;
#pragma unroll
        for (int w = 0; w < NW; ++w) A += xv[w];
        float hi = -0.5f * A;
        if (W & 2) hi += xv[0];
        if (W & 1) hi += xv[1];
#pragma unroll
        for (int j = 0; j < 6; ++j)
            hi += ((lane >> j) & 1) ? xv[7 - j] : 0.f;
        float lo[4];
        lo[0] = 0.f;   lo[1] = xv[9];
        lo[2] = xv[8]; lo[3] = xv[8] + xv[9];
#pragma unroll
        for (int r = 0; r < 4; ++r)
            __sincosf(hi + lo[r], &xi[r], &xr[r]);
    }

    int bs = 0;

    auto tdiag = [&](int d) {
        const float2* tb = tab + (d << 10) + ebase;
#pragma unroll
        for (int r = 0; r < 4; ++r) {
            const float2 p = tb[r << 6];
            const float a = re[r], bb = im[r];
            re[r] = a * p.x - bb * p.y;
            im[r] = a * p.y + bb * p.x;
        }
    };
    auto txdiag = [&](int d) {
        const float2* tb = tab + (d << 10) + ebase;
#pragma unroll
        for (int r = 0; r < 4; ++r) {
            const float2 p = tb[r << 6];
            const float cx = p.x * xr[r] - p.y * xi[r];
            const float sx = p.x * xi[r] + p.y * xr[r];
            const float a = re[r], bb = im[r];
            re[r] = a * cx - bb * sx;
            im[r] = a * sx + bb * cx;
        }
    };

    auto bfly_local = [&](float2 cw, int m) {
#pragma unroll
        for (int r = 0; r < 4; ++r) {
            if (!(r & m)) {
                const int r2 = r | m;
                float a = re[r], bb = re[r2];
                re[r]  = cw.x * a - cw.y * bb;
                re[r2] = cw.y * a + cw.x * bb;
                float ai = im[r], bi = im[r2];
                im[r]  = cw.x * ai - cw.y * bi;
                im[r2] = cw.y * ai + cw.x * bi;
            }
        }
    };

    // ry: phase A in C (wires 9,8 local; 7,6,4 DPP), retile C->L1, phase B (wires 1,0 local; 5,3,2 DPP).
    // Ends in L1 — following tdiag uses an L1 table, following perm restores C.
    auto ry = [&](int ridx) {
        const float2* rt = ry_tab + ridx * NW;
        bfly_local(rt[9], 1);
        bfly_local(rt[8], 2);
        {   const float2 cw = rt[7]; const float ss = (lane & 1) ? cw.y : -cw.y;
#pragma unroll
            for (int r = 0; r < 4; ++r) {
                float pre = fdpp<0xB1>(re[r]), pim = fdpp<0xB1>(im[r]);
                re[r] = cw.x * re[r] + ss * pre;
                im[r] = cw.x * im[r] + ss * pim;
            }
        }
        {   const float2 cw = rt[6]; const float ss = (lane & 2) ? cw.y : -cw.y;
#pragma unroll
            for (int r = 0; r < 4; ++r) {
                float pre = fdpp<0x4E>(re[r]), pim = fdpp<0x4E>(im[r]);
                re[r] = cw.x * re[r] + ss * pre;
                im[r] = cw.x * im[r] + ss * pim;
            }
        }
        {   const float2 cw = rt[4]; const float ss = (lane & 8) ? cw.y : -cw.y;
#pragma unroll
            for (int r = 0; r < 4; ++r) {
                float pre = fdpp<0x128>(re[r]), pim = fdpp<0x128>(im[r]);
                re[r] = cw.x * re[r] + ss * pre;
                im[r] = cw.x * im[r] + ss * pim;
            }
        }
        // retile C -> L1 (one barrier)
        {
            float2* B = buf[bs]; bs ^= 1;
#pragma unroll
            for (int r = 0; r < 4; ++r)
                B[ebase + (r << 6)] = make_float2(re[r], im[r]);
            __syncthreads();
#pragma unroll
            for (int r = 0; r < 4; ++r) {
                const float2 p = B[riA[r]];
                re[r] = p.x;
                im[r] = p.y;
            }
        }
        bfly_local(rt[1], 1);      // s8
        bfly_local(rt[0], 2);      // s9
        {   const float2 cw = rt[5]; const float ss = (lane & 1) ? cw.y : -cw.y;   // s4
#pragma unroll
            for (int r = 0; r < 4; ++r) {
                float pre = fdpp<0xB1>(re[r]), pim = fdpp<0xB1>(im[r]);
                re[r] = cw.x * re[r] + ss * pre;
                im[r] = cw.x * im[r] + ss * pim;
            }
        }
        {   const float2 cw = rt[3]; const float ss = (lane & 2) ? cw.y : -cw.y;   // s6
#pragma unroll
            for (int r = 0; r < 4; ++r) {
                float pre = fdpp<0x4E>(re[r]), pim = fdpp<0x4E>(im[r]);
                re[r] = cw.x * re[r] + ss * pre;
                im[r] = cw.x * im[r] + ss * pim;
            }
        }
        {   const float2 cw = rt[2]; const float ss = (lane & 8) ? cw.y : -cw.y;   // s7
#pragma unroll
            for (int r = 0; r < 4; ++r) {
                float pre = fdpp<0x128>(re[r]), pim = fdpp<0x128>(im[r]);
                re[r] = cw.x * re[r] + ss * pre;
                im[r] = cw.x * im[r] + ss * pim;
            }
        }
    };

    // perm (fused with L1->C restore): write in L1 coords, gather geidx -> canonical C
    auto perm = [&]() {
        float2* B = buf[bs]; bs ^= 1;
#pragma unroll
        for (int r = 0; r < 4; ++r)
            B[ebase + (r << 6)] = make_float2(re[r], im[r]);
        __syncthreads();
#pragma unroll
        for (int r = 0; r < 4; ++r) {
            const float2 p = B[geidx[r]];
            re[r] = p.x;
            im[r] = p.y;
        }
    };

#pragma unroll 1
    for (int k = 0; k < 4; ++k) {
        if (k > 0) txdiag(k - 1);       // enc(prev)+rz0(k) in C; k=0 rz0 = global phase
        ry(2 * k);                      // ends in L1
        tdiag(3 + k);                   // rz2, L1 table
        perm();                         // -> C
        tdiag(7 + k);                   // rz3, C table
        ry(2 * k + 1);                  // ends in L1
        if (k < 3) tdiag(11 + k);       // rz5, L1 table; k=3 pure phase (dropped)
        perm();                         // -> C
    }

    // out[b][w] = sum_s (re^2+im^2) * (1-2*bit_{9-w}(s))   (state in C)
    float pr[4];
#pragma unroll
    for (int r = 0; r < 4; ++r) pr[r] = re[r] * re[r] + im[r] * im[r];
    float S = 0.f;
#pragma unroll
    for (int r = 0; r < 4; ++r) S += pr[r];

    float acc[NW];
    acc[0] = (W & 2) ? -S : S;                 // s9
    acc[1] = (W & 1) ? -S : S;                 // s8
#pragma unroll
    for (int w = 2; w <= 7; ++w) {             // lane bit j = 7-w
        const int j = 7 - w;
        acc[w] = ((lane >> j) & 1) ? -S : S;
    }
    {
        float t8 = 0.f, t9 = 0.f;
#pragma unroll
        for (int r = 0; r < 4; ++r) {
            t8 += (r & 2) ? -pr[r] : pr[r];
            t9 += (r & 1) ? -pr[r] : pr[r];
        }
        acc[8] = t8; acc[9] = t9;
    }
#pragma unroll
    for (int w = 0; w < NW; ++w) {
        float a = acc[w];
        a += fdpp<0xB1>(a);
        a += fdpp<0x4E>(a);
        a += fswz<0x101F>(a);
        a += fdpp<0x128>(a);
        a += fswz<0x401F>(a);
        a += __shfl_xor(a, 32, 64);
        acc[w] = a;
    }
    if (lane == 0) {
#pragma unroll
        for (int w = 0; w < NW; ++w) sred[W][w] = acc[w];
    }
    __syncthreads();
    if (t < NW) out[b * NW + t] = sred[0][t] + sred[1][t] + sred[2][t] + sred[3][t];
}

extern "C" void kernel_launch(void* const* d_in, const int* in_sizes, int n_in,
                              void* d_out, int out_size, void* d_ws, size_t ws_size,
                              hipStream_t stream) {
    const float* x      = (const float*)d_in[0];   // (2048, 10)
    const float* params = (const float*)d_in[1];   // (4, 6, 10)
    float* out          = (float*)d_out;           // (1, 2048, 10)
    float2* tab         = (float2*)d_ws;           // 14*1024 + 80 float2 = 115 KB
    (void)in_sizes; (void)n_in; (void)out_size; (void)ws_size;
    precompute_kernel<<<15, 1024, 0, stream>>>(params, tab);
    qsim_kernel<<<2048, 256, 0, stream>>>(x, tab, out);
}

// Round 7
// 90.237 us; speedup vs baseline: 1.0177x; 1.0177x over previous
//
#include <hip/hip_runtime.h>

#define NW 10

// DPP: quad_perm xor1=0xB1, xor2=0x4E; row_ror:8 (xor8 within 16) = 0x128
template<int CTRL>
__device__ __forceinline__ float fdpp(float v) {
    return __int_as_float(__builtin_amdgcn_mov_dpp(__float_as_int(v), CTRL, 0xF, 0xF, true));
}
// ds_swizzle BitMode: xor4=0x101F, xor16=0x401F (final reduction only)
template<int PAT>
__device__ __forceinline__ float fswz(float v) {
    return __int_as_float(__builtin_amdgcn_ds_swizzle(__float_as_int(v), PAT));
}

// ---- Layouts ----
// C : r0=s0 r1=s1 | l0=s2 l1=s3 l2=s4 l3=s5 l4=s6 l5=s7 | W0=s8 W1=s9
// L1: r0=s8 r1=s9 | l0=s4 l1=s6 l2=s2 l3=s7 l4=s3 l5=s5 | W0=s0 W1=s1
__device__ __forceinline__ int sC(int W, int lane, int r) { return (W << 8) | (lane << 2) | r; }
__device__ __forceinline__ int sL1(int W, int lane, int r) {
    return ((r & 1) << 8) | (((r >> 1) & 1) << 9)
         | ((lane & 1) << 4) | (((lane >> 1) & 1) << 6) | (((lane >> 2) & 1) << 2)
         | (((lane >> 3) & 1) << 7) | (((lane >> 4) & 1) << 3) | (((lane >> 5) & 1) << 5)
         | ((W & 1) << 0) | (((W >> 1) & 1) << 1);
}

// ---------------- precompute: 14 diag tables (layout-aware) + 80 RY pairs ----------------
// d<3: rz0(k=d+1) [C] ; d<7: rz2(k=d-3) [L1] ; d<11: rz3(k=d-7) [C] ; d<14: rz5(k=d-11) [L1]
__global__ void precompute_kernel(const float* __restrict__ params, float2* __restrict__ tab) {
    const int d = blockIdx.x;
    const int j = threadIdx.x;
    if (d < 14) {
        int k, row; bool L1;
        if (d < 3)       { k = d + 1;  row = 0; L1 = false; }
        else if (d < 7)  { k = d - 3;  row = 2; L1 = true;  }
        else if (d < 11) { k = d - 7;  row = 3; L1 = false; }
        else             { k = d - 11; row = 5; L1 = true;  }
        const float* th = params + (k * 6 + row) * NW;
        const int W = j >> 8, lane = j & 63, r = (j >> 6) & 3;
        const int s = L1 ? sL1(W, lane, r) : sC(W, lane, r);
        float ang = 0.f;
#pragma unroll
        for (int w = 0; w < NW; ++w)
            ang += th[w] * (((s >> (9 - w)) & 1) ? 0.5f : -0.5f);
        float sn, cs;
        __sincosf(ang, &sn, &cs);
        tab[d * 1024 + j] = make_float2(cs, sn);
    } else if (j < 80) {
        const int ry = j / NW, w = j % NW;
        const int k = ry >> 1, i = ry & 1;
        const float* th = params + (k * 6 + (i ? 4 : 1)) * NW;
        float sn, cs;
        __sincosf(0.5f * th[w], &sn, &cs);
        tab[14 * 1024 + j] = make_float2(cs, sn);
    }
}

// ---------------- main kernel ----------------
__global__ __launch_bounds__(256, 8) void qsim_kernel(const float* __restrict__ x,
                                                      const float2* __restrict__ tab,
                                                      float* __restrict__ out) {
    __shared__ float2 buf[2][1024];
    __shared__ float sred[4][NW];

    const int t     = threadIdx.x;
    const int W     = t >> 6;
    const int lane  = t & 63;
    const int b     = blockIdx.x;
    const int ebase = lane | (W << 8);
    const float2* ry_tab = tab + 14 * 1024;

    float re[4], im[4];
#pragma unroll
    for (int r = 0; r < 4; ++r) { re[r] = 0.f; im[r] = 0.f; }
    if (t == 0) re[0] = 1.f;

    // Bank swizzle phi(e) = e ^ ((e>>1)&8)  [phi3 = e3^e4] — all patterns <=2-way.
    // Write base (own slot, swizzled); r<<6 offsets don't touch bits 3,4.
    const int wbase = ebase ^ ((lane >> 1) & 8);

    // Retile gather base: riA0 = eC(sL1(W,lane,0)); riA[r] = riA0 | r<<8 (bits 8,9 phi-safe)
    const int l0 = lane & 1, l1 = (lane >> 1) & 1, l2 = (lane >> 2) & 1,
              l3 = (lane >> 3) & 1, l4 = (lane >> 4) & 1, l5 = (lane >> 5) & 1;
    const int W0 = W & 1, W1 = (W >> 1) & 1;
    const int riA0 = l2 | (l4 << 1) | (l0 << 2) | (l5 << 3) | (l1 << 4) | (l3 << 5) | (W << 6);
    const int rgA  = riA0 ^ ((riA0 >> 1) & 8);

    // Perm gather: geidx[r] = g0 ^ (r0?0x1C0:0) ^ (r1?0x300:0); phi folded into g0.
    const int g0 = (l2 ^ l3) | ((l4 ^ l5) << 1) | ((l0 ^ l1) << 2) | ((l5 ^ W0) << 3)
                 | ((l1 ^ l2) << 4) | ((l3 ^ l4) << 5)
                 | ((W0 ^ W1) << 6) | (W1 << 7) | (l0 << 9);
    const int gP = g0 ^ ((g0 >> 1) & 8);

    // x-phase e^{iA_x(s)} (C layout), reused for the 3 encoding diagonals
    const float* xb = x + b * NW;
    float xr[4], xi[4];
    {
        float xv[NW];
#pragma unroll
        for (int w = 0; w < NW; ++w) xv[w] = xb[w];
        float A = 0.f;
#pragma unroll
        for (int w = 0; w < NW; ++w) A += xv[w];
        float hi = -0.5f * A;
        if (W & 2) hi += xv[0];
        if (W & 1) hi += xv[1];
#pragma unroll
        for (int j = 0; j < 6; ++j)
            hi += ((lane >> j) & 1) ? xv[7 - j] : 0.f;
        float lo[4];
        lo[0] = 0.f;   lo[1] = xv[9];
        lo[2] = xv[8]; lo[3] = xv[8] + xv[9];
#pragma unroll
        for (int r = 0; r < 4; ++r)
            __sincosf(hi + lo[r], &xi[r], &xr[r]);
    }

    int bs = 0;

    auto tdiag = [&](int d) {
        const float2* tb = tab + (d << 10) + ebase;
#pragma unroll
        for (int r = 0; r < 4; ++r) {
            const float2 p = tb[r << 6];
            const float a = re[r], bb = im[r];
            re[r] = a * p.x - bb * p.y;
            im[r] = a * p.y + bb * p.x;
        }
    };
    auto txdiag = [&](int d) {
        const float2* tb = tab + (d << 10) + ebase;
#pragma unroll
        for (int r = 0; r < 4; ++r) {
            const float2 p = tb[r << 6];
            const float cx = p.x * xr[r] - p.y * xi[r];
            const float sx = p.x * xi[r] + p.y * xr[r];
            const float a = re[r], bb = im[r];
            re[r] = a * cx - bb * sx;
            im[r] = a * sx + bb * cx;
        }
    };

    auto bfly_local = [&](float2 cw, int m) {
#pragma unroll
        for (int r = 0; r < 4; ++r) {
            if (!(r & m)) {
                const int r2 = r | m;
                float a = re[r], bb = re[r2];
                re[r]  = cw.x * a - cw.y * bb;
                re[r2] = cw.y * a + cw.x * bb;
                float ai = im[r], bi = im[r2];
                im[r]  = cw.x * ai - cw.y * bi;
                im[r2] = cw.y * ai + cw.x * bi;
            }
        }
    };

    // ry: phase A in C (wires 9,8 local; 7,6,4 via DPP), retile C->L1, phase B
    // (wires 1,0 local; 5,3,2 via DPP). Ends in L1.
    auto ry = [&](int ridx) {
        const float2* rt = ry_tab + ridx * NW;
        bfly_local(rt[9], 1);
        bfly_local(rt[8], 2);
        {   const float2 cw = rt[7]; const float ss = (lane & 1) ? cw.y : -cw.y;
#pragma unroll
            for (int r = 0; r < 4; ++r) {
                float pre = fdpp<0xB1>(re[r]), pim = fdpp<0xB1>(im[r]);
                re[r] = cw.x * re[r] + ss * pre;
                im[r] = cw.x * im[r] + ss * pim;
            }
        }
        {   const float2 cw = rt[6]; const float ss = (lane & 2) ? cw.y : -cw.y;
#pragma unroll
            for (int r = 0; r < 4; ++r) {
                float pre = fdpp<0x4E>(re[r]), pim = fdpp<0x4E>(im[r]);
                re[r] = cw.x * re[r] + ss * pre;
                im[r] = cw.x * im[r] + ss * pim;
            }
        }
        {   const float2 cw = rt[4]; const float ss = (lane & 8) ? cw.y : -cw.y;
#pragma unroll
            for (int r = 0; r < 4; ++r) {
                float pre = fdpp<0x128>(re[r]), pim = fdpp<0x128>(im[r]);
                re[r] = cw.x * re[r] + ss * pre;
                im[r] = cw.x * im[r] + ss * pim;
            }
        }
        // retile C -> L1 (swizzled, conflict-free, one barrier)
        {
            float2* B = buf[bs]; bs ^= 1;
#pragma unroll
            for (int r = 0; r < 4; ++r)
                B[wbase + (r << 6)] = make_float2(re[r], im[r]);
            __syncthreads();
#pragma unroll
            for (int r = 0; r < 4; ++r) {
                const float2 p = B[rgA + (r << 8)];
                re[r] = p.x;
                im[r] = p.y;
            }
        }
        bfly_local(rt[1], 1);      // s8
        bfly_local(rt[0], 2);      // s9
        {   const float2 cw = rt[5]; const float ss = (lane & 1) ? cw.y : -cw.y;   // s4
#pragma unroll
            for (int r = 0; r < 4; ++r) {
                float pre = fdpp<0xB1>(re[r]), pim = fdpp<0xB1>(im[r]);
                re[r] = cw.x * re[r] + ss * pre;
                im[r] = cw.x * im[r] + ss * pim;
            }
        }
        {   const float2 cw = rt[3]; const float ss = (lane & 2) ? cw.y : -cw.y;   // s6
#pragma unroll
            for (int r = 0; r < 4; ++r) {
                float pre = fdpp<0x4E>(re[r]), pim = fdpp<0x4E>(im[r]);
                re[r] = cw.x * re[r] + ss * pre;
                im[r] = cw.x * im[r] + ss * pim;
            }
        }
        {   const float2 cw = rt[2]; const float ss = (lane & 8) ? cw.y : -cw.y;   // s7
#pragma unroll
            for (int r = 0; r < 4; ++r) {
                float pre = fdpp<0x128>(re[r]), pim = fdpp<0x128>(im[r]);
                re[r] = cw.x * re[r] + ss * pre;
                im[r] = cw.x * im[r] + ss * pim;
            }
        }
    };

    // perm (fused with L1->C restore): write own L1 slot, gather gP^xc[r] -> canonical C
    auto perm = [&]() {
        float2* B = buf[bs]; bs ^= 1;
#pragma unroll
        for (int r = 0; r < 4; ++r)
            B[wbase + (r << 6)] = make_float2(re[r], im[r]);
        __syncthreads();
        constexpr int xc[4] = {0, 0x1C0, 0x300, 0x2C0};
#pragma unroll
        for (int r = 0; r < 4; ++r) {
            const float2 p = B[gP ^ xc[r]];
            re[r] = p.x;
            im[r] = p.y;
        }
    };

#pragma unroll 1
    for (int k = 0; k < 4; ++k) {
        if (k > 0) txdiag(k - 1);       // enc(prev)+rz0(k) in C; k=0 rz0 = global phase
        ry(2 * k);                      // ends in L1
        tdiag(3 + k);                   // rz2, L1 table
        perm();                         // -> C
        tdiag(7 + k);                   // rz3, C table
        ry(2 * k + 1);                  // ends in L1
        if (k < 3) tdiag(11 + k);       // rz5, L1 table; k=3 pure phase (dropped)
        perm();                         // -> C
    }

    // out[b][w] = sum_s (re^2+im^2) * (1-2*bit_{9-w}(s))   (state in C)
    float pr[4];
#pragma unroll
    for (int r = 0; r < 4; ++r) pr[r] = re[r] * re[r] + im[r] * im[r];
    float S = 0.f;
#pragma unroll
    for (int r = 0; r < 4; ++r) S += pr[r];

    float acc[NW];
    acc[0] = (W & 2) ? -S : S;                 // s9
    acc[1] = (W & 1) ? -S : S;                 // s8
#pragma unroll
    for (int w = 2; w <= 7; ++w) {             // lane bit j = 7-w
        const int j = 7 - w;
        acc[w] = ((lane >> j) & 1) ? -S : S;
    }
    {
        float t8 = 0.f, t9 = 0.f;
#pragma unroll
        for (int r = 0; r < 4; ++r) {
            t8 += (r & 2) ? -pr[r] : pr[r];
            t9 += (r & 1) ? -pr[r] : pr[r];
        }
        acc[8] = t8; acc[9] = t9;
    }
#pragma unroll
    for (int w = 0; w < NW; ++w) {
        float a = acc[w];
        a += fdpp<0xB1>(a);
        a += fdpp<0x4E>(a);
        a += fswz<0x101F>(a);
        a += fdpp<0x128>(a);
        a += fswz<0x401F>(a);
        a += __shfl_xor(a, 32, 64);
        acc[w] = a;
    }
    if (lane == 0) {
#pragma unroll
        for (int w = 0; w < NW; ++w) sred[W][w] = acc[w];
    }
    __syncthreads();
    if (t < NW) out[b * NW + t] = sred[0][t] + sred[1][t] + sred[2][t] + sred[3][t];
}

extern "C" void kernel_launch(void* const* d_in, const int* in_sizes, int n_in,
                              void* d_out, int out_size, void* d_ws, size_t ws_size,
                              hipStream_t stream) {
    const float* x      = (const float*)d_in[0];   // (2048, 10)
    const float* params = (const float*)d_in[1];   // (4, 6, 10)
    float* out          = (float*)d_out;           // (1, 2048, 10)
    float2* tab         = (float2*)d_ws;           // 14*1024 + 80 float2 = 115 KB
    (void)in_sizes; (void)n_in; (void)out_size; (void)ws_size;
    precompute_kernel<<<15, 1024, 0, stream>>>(params, tab);
    qsim_kernel<<<2048, 256, 0, stream>>>(x, tab, out);
}

// Round 8
// 87.580 us; speedup vs baseline: 1.0486x; 1.0303x over previous
//
#include <hip/hip_runtime.h>

#define NW 10

// DPP: quad_perm xor1=0xB1, xor2=0x4E; row_ror:8 (xor8 within 16) = 0x128
template<int CTRL>
__device__ __forceinline__ float fdpp(float v) {
    return __int_as_float(__builtin_amdgcn_mov_dpp(__float_as_int(v), CTRL, 0xF, 0xF, true));
}
// ds_swizzle BitMode: xor4=0x101F, xor16=0x401F (final reduction only)
template<int PAT>
__device__ __forceinline__ float fswz(float v) {
    return __int_as_float(__builtin_amdgcn_ds_swizzle(__float_as_int(v), PAT));
}

// ---- Layouts ----
// C : r0=s0 r1=s1 | l0=s2 l1=s3 l2=s4 l3=s5 l4=s6 l5=s7 | W0=s8 W1=s9
// L1: r0=s8 r1=s9 | l0=s4 l1=s6 l2=s2 l3=s7 l4=s3 l5=s5 | W0=s0 W1=s1
__device__ __forceinline__ int sC(int W, int lane, int r) { return (W << 8) | (lane << 2) | r; }
__device__ __forceinline__ int sL1(int W, int lane, int r) {
    return ((r & 1) << 8) | (((r >> 1) & 1) << 9)
         | ((lane & 1) << 4) | (((lane >> 1) & 1) << 6) | (((lane >> 2) & 1) << 2)
         | (((lane >> 3) & 1) << 7) | (((lane >> 4) & 1) << 3) | (((lane >> 5) & 1) << 5)
         | ((W & 1) << 0) | (((W >> 1) & 1) << 1);
}
// LDS bank swizzle: phi(e) = e ^ (e4<<3) ^ (e5<<1) — rank-4 bank bits per 16-lane
// group for all three access patterns (write own / retile gather / perm gather).
__device__ __forceinline__ int phi(int e) {
    return e ^ ((e & 0x10) >> 1) ^ ((e & 0x20) >> 4);
}

// ---------------- precompute: 14 diag tables (layout-aware) + 80 RY pairs ----------------
// d<3: rz0(k=d+1) [C] ; d<7: rz2(k=d-3) [L1] ; d<11: rz3(k=d-7) [C] ; d<14: rz5(k=d-11) [L1]
__global__ void precompute_kernel(const float* __restrict__ params, float2* __restrict__ tab) {
    const int d = blockIdx.x;
    const int j = threadIdx.x;
    if (d < 14) {
        int k, row; bool L1;
        if (d < 3)       { k = d + 1;  row = 0; L1 = false; }
        else if (d < 7)  { k = d - 3;  row = 2; L1 = true;  }
        else if (d < 11) { k = d - 7;  row = 3; L1 = false; }
        else             { k = d - 11; row = 5; L1 = true;  }
        const float* th = params + (k * 6 + row) * NW;
        const int W = j >> 8, lane = j & 63, r = (j >> 6) & 3;
        const int s = L1 ? sL1(W, lane, r) : sC(W, lane, r);
        float ang = 0.f;
#pragma unroll
        for (int w = 0; w < NW; ++w)
            ang += th[w] * (((s >> (9 - w)) & 1) ? 0.5f : -0.5f);
        float sn, cs;
        __sincosf(ang, &sn, &cs);
        tab[d * 1024 + j] = make_float2(cs, sn);
    } else if (j < 80) {
        const int ry = j / NW, w = j % NW;
        const int k = ry >> 1, i = ry & 1;
        const float* th = params + (k * 6 + (i ? 4 : 1)) * NW;
        float sn, cs;
        __sincosf(0.5f * th[w], &sn, &cs);
        tab[14 * 1024 + j] = make_float2(cs, sn);
    }
}

// ---------------- main kernel ----------------
// __launch_bounds__(256,4): VGPR cap 128 — compiler allocates ~48, no spill;
// actual occupancy stays 8 blocks/CU (grid-limited) because real VGPR use <= 64.
__global__ __launch_bounds__(256, 4) void qsim_kernel(const float* __restrict__ x,
                                                      const float2* __restrict__ tab,
                                                      float* __restrict__ out) {
    __shared__ float2 buf[2][1024];
    __shared__ float sred[4][NW];

    const int t     = threadIdx.x;
    const int W     = t >> 6;
    const int lane  = t & 63;
    const int b     = blockIdx.x;
    const int ebase = lane | (W << 8);
    const float2* ry_tab = tab + 14 * 1024;

    float re[4], im[4];
#pragma unroll
    for (int r = 0; r < 4; ++r) { re[r] = 0.f; im[r] = 0.f; }
    if (t == 0) re[0] = 1.f;

    // Write base (own slot, swizzled); r<<6 offsets don't touch bits 4,5.
    const int wbase = phi(ebase);

    const int l0 = lane & 1, l1 = (lane >> 1) & 1, l2 = (lane >> 2) & 1,
              l3 = (lane >> 3) & 1, l4 = (lane >> 4) & 1, l5 = (lane >> 5) & 1;
    const int W0 = W & 1, W1 = (W >> 1) & 1;
    // Retile gather base: eC(sL1(W,lane,0)); offsets r<<8 (phi-safe)
    const int riA0 = l2 | (l4 << 1) | (l0 << 2) | (l5 << 3) | (l1 << 4) | (l3 << 5) | (W << 6);
    const int rgA  = phi(riA0);
    // Perm gather: geidx[r] = g0 ^ {0,0x1C0,0x300,0x2C0}[r]; phi folded into g0 (masks hit bits>=6 only)
    const int g0 = (l2 ^ l3) | ((l4 ^ l5) << 1) | ((l0 ^ l1) << 2) | ((l5 ^ W0) << 3)
                 | ((l1 ^ l2) << 4) | ((l3 ^ l4) << 5)
                 | ((W0 ^ W1) << 6) | (W1 << 7) | (l0 << 9);
    const int gP = phi(g0);

    // x-phase e^{iA_x(s)} (C layout), reused for the 3 encoding diagonals
    const float* xb = x + b * NW;
    float xr[4], xi[4];
    {
        float xv[NW];
#pragma unroll
        for (int w = 0; w < NW; ++w) xv[w] = xb[w];
        float A = 0.f;
#pragma unroll
        for (int w = 0; w < NW; ++w) A += xv[w];
        float hi = -0.5f * A;
        if (W & 2) hi += xv[0];
        if (W & 1) hi += xv[1];
#pragma unroll
        for (int j = 0; j < 6; ++j)
            hi += ((lane >> j) & 1) ? xv[7 - j] : 0.f;
        float lo[4];
        lo[0] = 0.f;   lo[1] = xv[9];
        lo[2] = xv[8]; lo[3] = xv[8] + xv[9];
#pragma unroll
        for (int r = 0; r < 4; ++r)
            __sincosf(hi + lo[r], &xi[r], &xr[r]);
    }

    int bs = 0;

    auto tdiag = [&](int d) {
        const float2* tb = tab + (d << 10) + ebase;
#pragma unroll
        for (int r = 0; r < 4; ++r) {
            const float2 p = tb[r << 6];
            const float a = re[r], bb = im[r];
            re[r] = a * p.x - bb * p.y;
            im[r] = a * p.y + bb * p.x;
        }
    };
    auto txdiag = [&](int d) {
        const float2* tb = tab + (d << 10) + ebase;
#pragma unroll
        for (int r = 0; r < 4; ++r) {
            const float2 p = tb[r << 6];
            const float cx = p.x * xr[r] - p.y * xi[r];
            const float sx = p.x * xi[r] + p.y * xr[r];
            const float a = re[r], bb = im[r];
            re[r] = a * cx - bb * sx;
            im[r] = a * sx + bb * cx;
        }
    };

    auto bfly_local = [&](float2 cw, int m) {
#pragma unroll
        for (int r = 0; r < 4; ++r) {
            if (!(r & m)) {
                const int r2 = r | m;
                float a = re[r], bb = re[r2];
                re[r]  = cw.x * a - cw.y * bb;
                re[r2] = cw.y * a + cw.x * bb;
                float ai = im[r], bi = im[r2];
                im[r]  = cw.x * ai - cw.y * bi;
                im[r2] = cw.y * ai + cw.x * bi;
            }
        }
    };

    // ry: phase A in C (wires 9,8 local; 7,6,4 via DPP), retile C->L1, phase B
    // (wires 1,0 local; 5,3,2 via DPP). Ends in L1.
    auto ry = [&](int ridx) {
        const float2* rt = ry_tab + ridx * NW;
        bfly_local(rt[9], 1);
        bfly_local(rt[8], 2);
        {   const float2 cw = rt[7]; const float ss = (lane & 1) ? cw.y : -cw.y;
#pragma unroll
            for (int r = 0; r < 4; ++r) {
                float pre = fdpp<0xB1>(re[r]), pim = fdpp<0xB1>(im[r]);
                re[r] = cw.x * re[r] + ss * pre;
                im[r] = cw.x * im[r] + ss * pim;
            }
        }
        {   const float2 cw = rt[6]; const float ss = (lane & 2) ? cw.y : -cw.y;
#pragma unroll
            for (int r = 0; r < 4; ++r) {
                float pre = fdpp<0x4E>(re[r]), pim = fdpp<0x4E>(im[r]);
                re[r] = cw.x * re[r] + ss * pre;
                im[r] = cw.x * im[r] + ss * pim;
            }
        }
        {   const float2 cw = rt[4]; const float ss = (lane & 8) ? cw.y : -cw.y;
#pragma unroll
            for (int r = 0; r < 4; ++r) {
                float pre = fdpp<0x128>(re[r]), pim = fdpp<0x128>(im[r]);
                re[r] = cw.x * re[r] + ss * pre;
                im[r] = cw.x * im[r] + ss * pim;
            }
        }
        // retile C -> L1 (swizzled, conflict-free, one barrier)
        {
            float2* B = buf[bs]; bs ^= 1;
#pragma unroll
            for (int r = 0; r < 4; ++r)
                B[wbase + (r << 6)] = make_float2(re[r], im[r]);
            __syncthreads();
#pragma unroll
            for (int r = 0; r < 4; ++r) {
                const float2 p = B[rgA + (r << 8)];
                re[r] = p.x;
                im[r] = p.y;
            }
        }
        bfly_local(rt[1], 1);      // s8
        bfly_local(rt[0], 2);      // s9
        {   const float2 cw = rt[5]; const float ss = (lane & 1) ? cw.y : -cw.y;   // s4
#pragma unroll
            for (int r = 0; r < 4; ++r) {
                float pre = fdpp<0xB1>(re[r]), pim = fdpp<0xB1>(im[r]);
                re[r] = cw.x * re[r] + ss * pre;
                im[r] = cw.x * im[r] + ss * pim;
            }
        }
        {   const float2 cw = rt[3]; const float ss = (lane & 2) ? cw.y : -cw.y;   // s6
#pragma unroll
            for (int r = 0; r < 4; ++r) {
                float pre = fdpp<0x4E>(re[r]), pim = fdpp<0x4E>(im[r]);
                re[r] = cw.x * re[r] + ss * pre;
                im[r] = cw.x * im[r] + ss * pim;
            }
        }
        {   const float2 cw = rt[2]; const float ss = (lane & 8) ? cw.y : -cw.y;   // s7
#pragma unroll
            for (int r = 0; r < 4; ++r) {
                float pre = fdpp<0x128>(re[r]), pim = fdpp<0x128>(im[r]);
                re[r] = cw.x * re[r] + ss * pre;
                im[r] = cw.x * im[r] + ss * pim;
            }
        }
    };

    // perm (fused with L1->C restore): write own L1 slot, gather gP^xc[r] -> canonical C
    auto perm = [&]() {
        float2* B = buf[bs]; bs ^= 1;
#pragma unroll
        for (int r = 0; r < 4; ++r)
            B[wbase + (r << 6)] = make_float2(re[r], im[r]);
        __syncthreads();
        constexpr int xc[4] = {0, 0x1C0, 0x300, 0x2C0};
#pragma unroll
        for (int r = 0; r < 4; ++r) {
            const float2 p = B[gP ^ xc[r]];
            re[r] = p.x;
            im[r] = p.y;
        }
    };

#pragma unroll 1
    for (int k = 0; k < 4; ++k) {
        if (k > 0) txdiag(k - 1);       // enc(prev)+rz0(k) in C; k=0 rz0 = global phase
        ry(2 * k);                      // ends in L1
        tdiag(3 + k);                   // rz2, L1 table
        perm();                         // -> C
        tdiag(7 + k);                   // rz3, C table
        ry(2 * k + 1);                  // ends in L1
        if (k < 3) tdiag(11 + k);       // rz5, L1 table; k=3 pure phase (dropped)
        perm();                         // -> C
    }

    // out[b][w] = sum_s (re^2+im^2) * (1-2*bit_{9-w}(s))   (state in C)
    float pr[4];
#pragma unroll
    for (int r = 0; r < 4; ++r) pr[r] = re[r] * re[r] + im[r] * im[r];
    float S = 0.f;
#pragma unroll
    for (int r = 0; r < 4; ++r) S += pr[r];

    float acc[NW];
    acc[0] = (W & 2) ? -S : S;                 // s9
    acc[1] = (W & 1) ? -S : S;                 // s8
#pragma unroll
    for (int w = 2; w <= 7; ++w) {             // lane bit j = 7-w
        const int j = 7 - w;
        acc[w] = ((lane >> j) & 1) ? -S : S;
    }
    {
        float t8 = 0.f, t9 = 0.f;
#pragma unroll
        for (int r = 0; r < 4; ++r) {
            t8 += (r & 2) ? -pr[r] : pr[r];
            t9 += (r & 1) ? -pr[r] : pr[r];
        }
        acc[8] = t8; acc[9] = t9;
    }
#pragma unroll
    for (int w = 0; w < NW; ++w) {
        float a = acc[w];
        a += fdpp<0xB1>(a);
        a += fdpp<0x4E>(a);
        a += fswz<0x101F>(a);
        a += fdpp<0x128>(a);
        a += fswz<0x401F>(a);
        a += __shfl_xor(a, 32, 64);
        acc[w] = a;
    }
    if (lane == 0) {
#pragma unroll
        for (int w = 0; w < NW; ++w) sred[W][w] = acc[w];
    }
    __syncthreads();
    if (t < NW) out[b * NW + t] = sred[0][t] + sred[1][t] + sred[2][t] + sred[3][t];
}

extern "C" void kernel_launch(void* const* d_in, const int* in_sizes, int n_in,
                              void* d_out, int out_size, void* d_ws, size_t ws_size,
                              hipStream_t stream) {
    const float* x      = (const float*)d_in[0];   // (2048, 10)
    const float* params = (const float*)d_in[1];   // (4, 6, 10)
    float* out          = (float*)d_out;           // (1, 2048, 10)
    float2* tab         = (float2*)d_ws;           // 14*1024 + 80 float2 = 115 KB
    (void)in_sizes; (void)n_in; (void)out_size; (void)ws_size;
    precompute_kernel<<<15, 1024, 0, stream>>>(params, tab);
    qsim_kernel<<<2048, 256, 0, stream>>>(x, tab, out);
}

// Round 9
// 83.492 us; speedup vs baseline: 1.1000x; 1.0490x over previous
//
#include <hip/hip_runtime.h>

#define NW 10

typedef float v2f __attribute__((ext_vector_type(2)));
typedef float v4f __attribute__((ext_vector_type(4)));

// DPP: quad_perm xor1=0xB1, xor2=0x4E; row_ror:8 (xor8 within 16) = 0x128
template<int CTRL>
__device__ __forceinline__ float fdpp(float v) {
    return __int_as_float(__builtin_amdgcn_mov_dpp(__float_as_int(v), CTRL, 0xF, 0xF, true));
}
// ds_swizzle BitMode: xor4=0x101F, xor16=0x401F (final reduction only)
template<int PAT>
__device__ __forceinline__ float fswz(float v) {
    return __int_as_float(__builtin_amdgcn_ds_swizzle(__float_as_int(v), PAT));
}

// ---- Layouts ----
// C : r0=s0 r1=s1 | l0=s2 l1=s3 l2=s4 l3=s5 l4=s6 l5=s7 | W0=s8 W1=s9
// L1: r0=s8 r1=s9 | l0=s4 l1=s6 l2=s2 l3=s7 l4=s3 l5=s5 | W0=s0 W1=s1
__device__ __forceinline__ int sC(int W, int lane, int r) { return (W << 8) | (lane << 2) | r; }
__device__ __forceinline__ int sL1(int W, int lane, int r) {
    return ((r & 1) << 8) | (((r >> 1) & 1) << 9)
         | ((lane & 1) << 4) | (((lane >> 1) & 1) << 6) | (((lane >> 2) & 1) << 2)
         | (((lane >> 3) & 1) << 7) | (((lane >> 4) & 1) << 3) | (((lane >> 5) & 1) << 5)
         | ((W & 1) << 0) | (((W >> 1) & 1) << 1);
}
// LDS bank swizzle: phi(e) = e ^ (e4<<3) ^ (e5<<1)
__device__ __forceinline__ int phi(int e) {
    return e ^ ((e & 0x10) >> 1) ^ ((e & 0x20) >> 4);
}

// ---------------- precompute: 14 diag tables [c,s,-s,c] + 80 RY (cos,sin) ----------------
// d<3: rz0(k=d+1) [C] ; d<7: rz2(k=d-3) [L1] ; d<11: rz3(k=d-7) [C] ; d<14: rz5(k=d-11) [L1]
__global__ void precompute_kernel(const float* __restrict__ params, float4* __restrict__ tab4) {
    const int d = blockIdx.x;
    const int j = threadIdx.x;
    if (d < 14) {
        int k, row; bool L1;
        if (d < 3)       { k = d + 1;  row = 0; L1 = false; }
        else if (d < 7)  { k = d - 3;  row = 2; L1 = true;  }
        else if (d < 11) { k = d - 7;  row = 3; L1 = false; }
        else             { k = d - 11; row = 5; L1 = true;  }
        const float* th = params + (k * 6 + row) * NW;
        const int W = j >> 8, lane = j & 63, r = (j >> 6) & 3;
        const int s = L1 ? sL1(W, lane, r) : sC(W, lane, r);
        float ang = 0.f;
#pragma unroll
        for (int w = 0; w < NW; ++w)
            ang += th[w] * (((s >> (9 - w)) & 1) ? 0.5f : -0.5f);
        float sn, cs;
        __sincosf(ang, &sn, &cs);
        tab4[d * 1024 + j] = make_float4(cs, sn, -sn, cs);
    } else if (j < 80) {
        const int ry = j / NW, w = j % NW;
        const int k = ry >> 1, i = ry & 1;
        const float* th = params + (k * 6 + (i ? 4 : 1)) * NW;
        float sn, cs;
        __sincosf(0.5f * th[w], &sn, &cs);
        float2* ryt = (float2*)(tab4 + 14 * 1024);
        ryt[j] = make_float2(cs, sn);
    }
}

// ---------------- main kernel ----------------
__global__ __launch_bounds__(256, 4) void qsim_kernel(const float* __restrict__ x,
                                                      const v4f* __restrict__ tab4,
                                                      float* __restrict__ out) {
    __shared__ v2f buf[2][1024];
    __shared__ float sred[4][NW];

    const int t     = threadIdx.x;
    const int W     = t >> 6;
    const int lane  = t & 63;
    const int b     = blockIdx.x;
    const int ebase = lane | (W << 8);
    const float2* ry_tab = (const float2*)(tab4 + 14 * 1024);

    v2f st[4];
#pragma unroll
    for (int r = 0; r < 4; ++r) st[r] = (v2f){0.f, 0.f};
    if (t == 0) st[0].x = 1.f;

    const int wbase = phi(ebase);
    const int l0 = lane & 1, l1 = (lane >> 1) & 1, l2 = (lane >> 2) & 1,
              l3 = (lane >> 3) & 1, l4 = (lane >> 4) & 1, l5 = (lane >> 5) & 1;
    const int W0 = W & 1, W1 = (W >> 1) & 1;
    const int riA0 = l2 | (l4 << 1) | (l0 << 2) | (l5 << 3) | (l1 << 4) | (l3 << 5) | (W << 6);
    const int rgA  = phi(riA0);
    const int g0 = (l2 ^ l3) | ((l4 ^ l5) << 1) | ((l0 ^ l1) << 2) | ((l5 ^ W0) << 3)
                 | ((l1 ^ l2) << 4) | ((l3 ^ l4) << 5)
                 | ((W0 ^ W1) << 6) | (W1 << 7) | (l0 << 9);
    const int gP = phi(g0);

    // x-phase e^{iA_x(s)} (C layout) as v2f [xc, xs]
    const float* xb = x + b * NW;
    v2f xp[4];
    {
        float xv[NW];
#pragma unroll
        for (int w = 0; w < NW; ++w) xv[w] = xb[w];
        float A = 0.f;
#pragma unroll
        for (int w = 0; w < NW; ++w) A += xv[w];
        float hi = -0.5f * A;
        if (W & 2) hi += xv[0];
        if (W & 1) hi += xv[1];
#pragma unroll
        for (int j = 0; j < 6; ++j)
            hi += ((lane >> j) & 1) ? xv[7 - j] : 0.f;
        float lo[4];
        lo[0] = 0.f;   lo[1] = xv[9];
        lo[2] = xv[8]; lo[3] = xv[8] + xv[9];
#pragma unroll
        for (int r = 0; r < 4; ++r) {
            float sn, cs;
            __sincosf(hi + lo[r], &sn, &cs);
            xp[r] = (v2f){cs, sn};
        }
    }

    int bs = 0;
    v4f tq[4];   // prefetched diagonal entries (issued before barrier-bearing ops)

    auto pre = [&](int d) {
        const v4f* tb = tab4 + (d << 10) + ebase;
#pragma unroll
        for (int r = 0; r < 4; ++r) tq[r] = tb[r << 6];
    };
    auto apply_t = [&]() {
#pragma unroll
        for (int r = 0; r < 4; ++r)
            st[r] = st[r].x * tq[r].xy + st[r].y * tq[r].zw;
    };
    auto apply_tx = [&]() {
#pragma unroll
        for (int r = 0; r < 4; ++r) {
            const v2f c = xp[r].x * tq[r].xy + xp[r].y * tq[r].zw;
            const v2f cq = (v2f){-c.y, c.x};
            st[r] = st[r].x * c + st[r].y * cq;
        }
    };

    auto bfly_local = [&](float2 cw, int m) {
#pragma unroll
        for (int r = 0; r < 4; ++r) {
            if (!(r & m)) {
                const int r2 = r | m;
                const v2f a = st[r];
                st[r]  = cw.x * a - cw.y * st[r2];
                st[r2] = cw.y * a + cw.x * st[r2];
            }
        }
    };

    auto ry = [&](int ridx) {
        const float2* rt = ry_tab + ridx * NW;
        bfly_local(rt[9], 1);
        bfly_local(rt[8], 2);
        {   const float2 cw = rt[7]; const float ss = (lane & 1) ? cw.y : -cw.y;
#pragma unroll
            for (int r = 0; r < 4; ++r) {
                v2f p; p.x = fdpp<0xB1>(st[r].x); p.y = fdpp<0xB1>(st[r].y);
                st[r] = cw.x * st[r] + ss * p;
            }
        }
        {   const float2 cw = rt[6]; const float ss = (lane & 2) ? cw.y : -cw.y;
#pragma unroll
            for (int r = 0; r < 4; ++r) {
                v2f p; p.x = fdpp<0x4E>(st[r].x); p.y = fdpp<0x4E>(st[r].y);
                st[r] = cw.x * st[r] + ss * p;
            }
        }
        {   const float2 cw = rt[4]; const float ss = (lane & 8) ? cw.y : -cw.y;
#pragma unroll
            for (int r = 0; r < 4; ++r) {
                v2f p; p.x = fdpp<0x128>(st[r].x); p.y = fdpp<0x128>(st[r].y);
                st[r] = cw.x * st[r] + ss * p;
            }
        }
        // retile C -> L1 (swizzled, one barrier)
        {
            v2f* B = buf[bs]; bs ^= 1;
#pragma unroll
            for (int r = 0; r < 4; ++r)
                B[wbase + (r << 6)] = st[r];
            __syncthreads();
#pragma unroll
            for (int r = 0; r < 4; ++r)
                st[r] = B[rgA + (r << 8)];
        }
        bfly_local(rt[1], 1);      // s8
        bfly_local(rt[0], 2);      // s9
        {   const float2 cw = rt[5]; const float ss = (lane & 1) ? cw.y : -cw.y;   // s4
#pragma unroll
            for (int r = 0; r < 4; ++r) {
                v2f p; p.x = fdpp<0xB1>(st[r].x); p.y = fdpp<0xB1>(st[r].y);
                st[r] = cw.x * st[r] + ss * p;
            }
        }
        {   const float2 cw = rt[3]; const float ss = (lane & 2) ? cw.y : -cw.y;   // s6
#pragma unroll
            for (int r = 0; r < 4; ++r) {
                v2f p; p.x = fdpp<0x4E>(st[r].x); p.y = fdpp<0x4E>(st[r].y);
                st[r] = cw.x * st[r] + ss * p;
            }
        }
        {   const float2 cw = rt[2]; const float ss = (lane & 8) ? cw.y : -cw.y;   // s7
#pragma unroll
            for (int r = 0; r < 4; ++r) {
                v2f p; p.x = fdpp<0x128>(st[r].x); p.y = fdpp<0x128>(st[r].y);
                st[r] = cw.x * st[r] + ss * p;
            }
        }
    };

    auto perm = [&]() {
        v2f* B = buf[bs]; bs ^= 1;
#pragma unroll
        for (int r = 0; r < 4; ++r)
            B[wbase + (r << 6)] = st[r];
        __syncthreads();
        constexpr int xc[4] = {0, 0x1C0, 0x300, 0x2C0};
#pragma unroll
        for (int r = 0; r < 4; ++r)
            st[r] = B[gP ^ xc[r]];
    };

#pragma unroll 1
    for (int k = 0; k < 4; ++k) {
        if (k > 0) apply_tx();          // enc(prev)+rz0(k), tq prefetched last iter
        pre(3 + k);
        ry(2 * k);                      // barrier inside
        apply_t();                      // rz2, L1
        pre(7 + k);
        perm();                         // barrier
        apply_t();                      // rz3, C
        if (k < 3) pre(11 + k);
        ry(2 * k + 1);                  // barrier
        if (k < 3) { apply_t(); pre(k); }   // rz5 (L1); prefetch next txdiag (C)
        perm();                         // barrier
    }

    // out[b][w] = sum_s |st|^2 * (1-2*bit_{9-w}(s))   (state in C)
    float pr[4];
#pragma unroll
    for (int r = 0; r < 4; ++r) pr[r] = st[r].x * st[r].x + st[r].y * st[r].y;
    float S = 0.f;
#pragma unroll
    for (int r = 0; r < 4; ++r) S += pr[r];

    float acc[NW];
    acc[0] = (W & 2) ? -S : S;                 // s9
    acc[1] = (W & 1) ? -S : S;                 // s8
#pragma unroll
    for (int w = 2; w <= 7; ++w) {             // lane bit j = 7-w
        const int j = 7 - w;
        acc[w] = ((lane >> j) & 1) ? -S : S;
    }
    {
        float t8 = 0.f, t9 = 0.f;
#pragma unroll
        for (int r = 0; r < 4; ++r) {
            t8 += (r & 2) ? -pr[r] : pr[r];
            t9 += (r & 1) ? -pr[r] : pr[r];
        }
        acc[8] = t8; acc[9] = t9;
    }
#pragma unroll
    for (int w = 0; w < NW; ++w) {
        float a = acc[w];
        a += fdpp<0xB1>(a);
        a += fdpp<0x4E>(a);
        a += fswz<0x101F>(a);
        a += fdpp<0x128>(a);
        a += fswz<0x401F>(a);
        a += __shfl_xor(a, 32, 64);
        acc[w] = a;
    }
    if (lane == 0) {
#pragma unroll
        for (int w = 0; w < NW; ++w) sred[W][w] = acc[w];
    }
    __syncthreads();
    if (t < NW) out[b * NW + t] = sred[0][t] + sred[1][t] + sred[2][t] + sred[3][t];
}

extern "C" void kernel_launch(void* const* d_in, const int* in_sizes, int n_in,
                              void* d_out, int out_size, void* d_ws, size_t ws_size,
                              hipStream_t stream) {
    const float* x      = (const float*)d_in[0];   // (2048, 10)
    const float* params = (const float*)d_in[1];   // (4, 6, 10)
    float* out          = (float*)d_out;           // (1, 2048, 10)
    float4* tab4        = (float4*)d_ws;           // 14*1024 float4 + 80 float2 = 225 KB
    (void)in_sizes; (void)n_in; (void)out_size; (void)ws_size;
    precompute_kernel<<<15, 1024, 0, stream>>>(params, tab4);
    qsim_kernel<<<2048, 256, 0, stream>>>(x, (const v4f*)tab4, out);
}